// Round 3
// baseline (113.051 us; speedup 1.0000x reference)
//
#include <hip/hip_runtime.h>
#include <hip/hip_bf16.h>
#include <cstdint>

typedef __attribute__((ext_vector_type(8))) short bf16x8;
typedef __attribute__((ext_vector_type(4))) float f32x4;

static __device__ __forceinline__ float lo16(uint32_t u){ return __uint_as_float(u << 16); }
static __device__ __forceinline__ float hi16(uint32_t u){ return __uint_as_float(u & 0xffff0000u); }
static __device__ __forceinline__ uint32_t f2bf(float x){
    uint32_t u = __float_as_uint(x);
    return (u + 0x7fffu + ((u >> 16) & 1u)) >> 16;
}
static __device__ __forceinline__ uint32_t pack2(float a, float b){
    return f2bf(a) | (f2bf(b) << 16);
}
static __device__ __forceinline__ uint32_t cvtpk(float a, float b){
    uint32_t r;
    asm("v_cvt_pk_bf16_f32 %0, %1, %2" : "=v"(r) : "v"(a), "v"(b));
    return r;
}
static __device__ __forceinline__ void pl32swap(uint32_t &x, uint32_t &y){
    asm("v_permlane32_swap_b32 %0, %1" : "+v"(x), "+v"(y));
}
static __device__ __forceinline__ void pl16swap(uint32_t &x, uint32_t &y){
    asm("v_permlane16_swap_b32 %0, %1" : "+v"(x), "+v"(y));
}
typedef const __attribute__((address_space(1))) uint32_t* gas_u32p;
typedef __attribute__((address_space(3))) uint32_t* las_u32p;
static __device__ __forceinline__ void gload_lds16(const uint32_t* g, uint32_t* l){
    __builtin_amdgcn_global_load_lds((gas_u32p)g, (las_u32p)l, 16, 0, 0);
}

// ---------------- K1: fused kf + qb projections, pre-swizzled image outputs ----
// grid 512: blocks 0..255 = qb (bg, j-half), blocks 256..511 = kf (b, i-group)
// Outputs are written in the EXACT LDS image layout k_attn stages linearly:
//   kf_img[b][8192 u32]: i*16 + (((dp>>2)^(i&3))&3)*4 + (dp&3)   (dp = d>>1, pair over d)
//   qb_img[bg][8192 u32]: d*256 + (((j>>3)^(d&7))&63)*4 + ((j&7)>>1)  (pair over j)
__global__ __launch_bounds__(1024) void k_pre(const float* __restrict__ q,
    const float* __restrict__ k,
    const float* __restrict__ Wq, const float* __restrict__ bq,
    const float* __restrict__ Wk, const float* __restrict__ bk,
    uint32_t* __restrict__ qb_img, uint32_t* __restrict__ kf_img)
{
    __shared__ float buf[9248];
    int t = threadIdx.x;
    int blk = blockIdx.x;
    if (blk < 256){
        // ---------- qb projection ----------
        float* Wq_s = buf;            // 1024
        float* bq_s = buf + 1024;     // 32
        float* q_s  = buf + 1056;     // 8192  (layout [c][j], 32 x 256)
        int bg = blk >> 1, h = blk & 1;
        int b = bg >> 6, g = bg & 63;
        int bh = g >> 4, bw = (g >> 2) & 3, bd = g & 3;
        Wq_s[t & 1023] = Wq[t & 1023];
        if (t < 32) bq_s[t] = bq[t];
        const float* qbase = q + (size_t)b * 1048576;
        #pragma unroll
        for (int m = 0; m < 2; ++m){
            int L4 = m*1024 + t;
            int f4 = L4 & 1, iw = (L4 >> 1) & 7, ihl = (L4 >> 4) & 3, c = L4 >> 6;
            const float* src = qbase + c*32768 + (bh*8 + h*4 + ihl)*1024
                             + (bw*8 + iw)*32 + bd*8 + f4*4;
            float4 v = *(const float4*)src;
            *(float4*)&q_s[c*256 + ihl*64 + iw*8 + f4*4] = v;
        }
        __syncthreads();
        int d = t & 31, sub = t >> 5;      // sub 0..31
        float wq[32];
        #pragma unroll
        for (int c = 0; c < 32; ++c) wq[c] = Wq_s[c*32 + d];
        uint32_t* qb_out = qb_img + (size_t)bg * 8192;
        #pragma unroll
        for (int it = 0; it < 2; ++it){
            int jl = it*128 + sub*4;
            float bb = bq_s[d];
            float a0 = bb, a1 = bb, a2 = bb, a3 = bb;
            #pragma unroll
            for (int c = 0; c < 32; ++c){
                float4 qv = *(const float4*)&q_s[c*256 + jl];
                a0 += qv.x * wq[c];
                a1 += qv.y * wq[c];
                a2 += qv.z * wq[c];
                a3 += qv.w * wq[c];
            }
            int jg = h*256 + jl;                       // global j 0..511, mult of 4
            int grp = ((jg >> 3) ^ (d & 7)) & 63;
            int word = (jg & 7) >> 1;                  // 0 or 2
            uint2 wv;
            wv.x = pack2(a0, a1);
            wv.y = pack2(a2, a3);
            *(uint2*)&qb_out[d*256 + grp*4 + word] = wv;
        }
    } else {
        // ---------- kf projection ----------
        float* Wk_s = buf;            // 8192
        float* bk_s = buf + 8192;     // 32
        float* red  = buf + 8224;     // 1024 (32 x 32)
        for (int L = t; L < 8192; L += 1024) Wk_s[L] = Wk[L];
        if (t < 32) bk_s[t] = bk[t];
        __syncthreads();
        int kb_blk = blk - 256;
        int b = kb_blk >> 7, i0 = (kb_blk & 127) * 4;
        int d = t & 31, sub = t >> 5;
        int i = i0 + (sub >> 3);
        int cp = sub & 7;
        const float* kbp = k + (size_t)b * 131072;
        float acc = 0.f;
        #pragma unroll 8
        for (int cc = 0; cc < 32; ++cc){
            int c = cp*32 + cc;
            acc += kbp[c*512 + i] * Wk_s[c*32 + d];
        }
        red[sub*32 + d] = acc;
        __syncthreads();
        if (t < 128){
            int isel = t >> 5, dd = t & 31;
            float s = bk_s[dd];
            #pragma unroll
            for (int cp2 = 0; cp2 < 8; ++cp2) s += red[(isel*8 + cp2)*32 + dd];
            float sO = __shfl_xor(s, 1, 64);
            if ((dd & 1) == 0){
                int dp = dd >> 1;
                int ii = i0 + isel;
                kf_img[b*8192 + ii*16 + (((dp>>2) ^ (ii&3)) & 3)*4 + (dp&3)] = pack2(s, sO);
            }
        }
    }
}

// ---------------- K2: MFMA attention, linear global_load_lds staging ----------
// grid 512 = (bg, j-quarter); block 512 = 8 waves; ~74 KB LDS -> 2 blocks/CU.
// Swapped QK^T (A=kf,B=qb); exp+cvt_pk+permlane builds PV B-fragment in registers.
__global__ __launch_bounds__(512) void k_attn_mfma(const uint32_t* __restrict__ kf_img,
    const uint32_t* __restrict__ qb_img,
    float* __restrict__ oraw, float* __restrict__ mnp, float* __restrict__ mxp)
{
    __shared__ uint32_t kfs32[8192];     // 32 KB: kf [512 i][16 dp] swizzled
    __shared__ uint16_t qbV16[16384];    // 32 KB: qb^T [32 d][512 i] swizzled
    __shared__ float statA[32][32];      // 4 KB
    __shared__ float statB[16][32];      // 2 KB
    __shared__ float statC[16][32];      // 2 KB
    __shared__ float mred[8][64];        // 2 KB
    __shared__ float vssh[32];
    __shared__ float denom_s;
    int t = threadIdx.x;
    int blk = blockIdx.x;
    int bg = blk >> 2, jq = blk & 3;
    int b = bg >> 6;
    int wave = t >> 6, lane = t & 63;
    // ---- stage kf + qbV: linear async copy of pre-swizzled images ----
    {
        const uint32_t* gk = kf_img + b*8192;
        const uint32_t* gq = qb_img + (size_t)bg*8192;
        uint32_t* lq = (uint32_t*)qbV16;
        #pragma unroll
        for (int m = 0; m < 4; ++m){
            int off = wave*1024 + m*256;             // u32 units; wave-uniform
            gload_lds16(gk + off + lane*4, kfs32 + off);
        }
        #pragma unroll
        for (int m = 0; m < 4; ++m){
            int off = wave*1024 + m*256;
            gload_lds16(gq + off + lane*4, lq + off);
        }
    }
    __syncthreads();
    // ---- prologue: knorm2 / qn2 / vsum partials (one pass, one barrier) ----
    {
        int dp = t & 15, ig = t >> 4;            // 32 groups of 16 i
        float lo2 = 0.f, hi2 = 0.f;
        #pragma unroll
        for (int ii = 0; ii < 16; ++ii){
            int i = ig*16 + ii;
            uint32_t u = kfs32[i*16 + (((dp>>2) ^ (i&3)) & 3)*4 + (dp&3)];
            float a = lo16(u), c = hi16(u);
            lo2 += a*a; hi2 += c*c;
        }
        statA[ig][dp*2] = lo2; statA[ig][dp*2+1] = hi2;
    }
    {
        int d = t & 31, ig = t >> 5;             // 16 groups of 32 i
        float q2 = 0.f, vs = 0.f;
        #pragma unroll
        for (int ii = 0; ii < 32; ii += 2){
            int i = ig*32 + ii;
            uint32_t u = *(__shared__ uint32_t*)&qbV16[d*512 + (((i>>3) ^ (d&7)) & 63)*8 + (i&7)];
            float a = lo16(u), c = hi16(u);
            q2 += a*a + c*c; vs += a + c;
        }
        statB[ig][d] = q2; statC[ig][d] = vs;
    }
    __syncthreads();
    if (t < 32){
        float kn = 0.f;
        #pragma unroll
        for (int u = 0; u < 32; ++u) kn += statA[u][t];
        float q2 = 0.f, vs = 0.f;
        #pragma unroll
        for (int u = 0; u < 16; ++u){ q2 += statB[u][t]; vs += statC[u][t]; }
        vssh[t] = vs;
        float dv = sqrtf(kn) * sqrtf(q2);
        dv += __shfl_xor(dv, 1, 64);
        dv += __shfl_xor(dv, 2, 64);
        dv += __shfl_xor(dv, 4, 64);
        dv += __shfl_xor(dv, 8, 64);
        dv += __shfl_xor(dv, 16, 64);
        if (t == 0) denom_s = dv + 1e-4f;
    }
    __syncthreads();
    float rden = 1.0f / denom_s;
    int ln15 = lane & 15, quad = lane >> 4;
    float vs0[4], vs1[4];
    #pragma unroll
    for (int r = 0; r < 4; ++r){
        vs0[r] = vssh[quad*4 + r];
        vs1[r] = vssh[16 + quad*4 + r];
    }
    float* obase = oraw + (size_t)bg * 16384;
    int jloc = jq*128 + wave*16 + ln15;          // j within bg (0..511)
    union { bf16x8 v; uint16_t u[8]; } afr;
    #pragma unroll
    for (int jj = 0; jj < 8; ++jj){
        int d = quad*8 + jj;
        afr.u[jj] = qbV16[d*512 + (((jloc>>3) ^ (d&7)) & 63)*8 + (jloc&7)];
    }
    f32x4 pv0 = {0.f,0.f,0.f,0.f}, pv1 = {0.f,0.f,0.f,0.f};
    float pdn = 0.f;
    for (int sb = 0; sb < 4; ++sb){
        #pragma unroll
        for (int ch = 0; ch < 4; ++ch){
            int ib = sb*128 + ch*32;
            int i0 = ib + ln15;
            int i1 = i0 + 16;
            bf16x8 k0 = *(__shared__ bf16x8*)&kfs32[i0*16 + ((quad ^ (i0&3)) & 3)*4];
            bf16x8 k1 = *(__shared__ bf16x8*)&kfs32[i1*16 + ((quad ^ (i1&3)) & 3)*4];
            f32x4 z = {0.f,0.f,0.f,0.f};
            f32x4 s0 = __builtin_amdgcn_mfma_f32_16x16x32_bf16(k0, afr.v, z, 0, 0, 0);
            f32x4 s1 = __builtin_amdgcn_mfma_f32_16x16x32_bf16(k1, afr.v, z, 0, 0, 0);
            float e0[4], e1[4];
            #pragma unroll
            for (int r = 0; r < 4; ++r){
                float x = s0[r] * rden;
                e0[r] = x + x*x*(0.5f + x*(1.0f/6.0f));
                pdn += e0[r];
                x = s1[r] * rden;
                e1[r] = x + x*x*(0.5f + x*(1.0f/6.0f));
                pdn += e1[r];
            }
            uint32_t A0 = cvtpk(e0[0], e0[1]);
            uint32_t A1 = cvtpk(e0[2], e0[3]);
            uint32_t B0 = cvtpk(e1[0], e1[1]);
            uint32_t B1 = cvtpk(e1[2], e1[3]);
            pl32swap(A0, B0); pl16swap(A0, B0);
            pl32swap(A1, B1); pl16swap(A1, B1);
            union { bf16x8 v; uint32_t w[4]; } bp;
            bp.w[0] = A0; bp.w[1] = A1; bp.w[2] = B0; bp.w[3] = B1;
            int ig = ib + quad*8;
            int c0 = ln15, c1 = 16 + ln15;
            bf16x8 av0 = *(__shared__ bf16x8*)&qbV16[c0*512 + (((ig>>3) ^ (c0&7)) & 63)*8];
            bf16x8 av1 = *(__shared__ bf16x8*)&qbV16[c1*512 + (((ig>>3) ^ (c1&7)) & 63)*8];
            pv0 = __builtin_amdgcn_mfma_f32_16x16x32_bf16(av0, bp.v, pv0, 0, 0, 0);
            pv1 = __builtin_amdgcn_mfma_f32_16x16x32_bf16(av1, bp.v, pv1, 0, 0, 0);
        }
    }
    // ---- epilogue: denom (quad reduce), o write, min/max ----
    pdn += __shfl_xor(pdn, 16, 64);
    pdn += __shfl_xor(pdn, 32, 64);
    float rl = 1.0f / (512.f + pdn);
    float o0[4], o1[4];
    #pragma unroll
    for (int r = 0; r < 4; ++r){
        o0[r] = (vs0[r] + pv0[r]) * rl;
        o1[r] = (vs1[r] + pv1[r]) * rl;
        obase[(quad*4 + r)*512 + jloc]      = o0[r];
        obase[(16 + quad*4 + r)*512 + jloc] = o1[r];
    }
    #pragma unroll
    for (int r = 0; r < 4; ++r){
        float mnA = o0[r], mxA = o0[r], mnB = o1[r], mxB = o1[r];
        #pragma unroll
        for (int off = 1; off < 16; off <<= 1){
            mnA = fminf(mnA, __shfl_xor(mnA, off, 64));
            mxA = fmaxf(mxA, __shfl_xor(mxA, off, 64));
            mnB = fminf(mnB, __shfl_xor(mnB, off, 64));
            mxB = fmaxf(mxB, __shfl_xor(mxB, off, 64));
        }
        if (ln15 == 0){
            mred[wave][quad*4 + r]      = mnA;
            mred[wave][32 + quad*4 + r] = mxA;
            mred[wave][16 + quad*4 + r] = mnB;
            mred[wave][48 + quad*4 + r] = mxB;
        }
    }
    __syncthreads();
    if (t < 32){
        float mn = 3e38f, mx = -3e38f;
        #pragma unroll
        for (int w = 0; w < 8; ++w){
            mn = fminf(mn, mred[w][t]);
            mx = fmaxf(mx, mred[w][32 + t]);
        }
        int slot = (bg*4 + jq)*32 + t;
        mnp[slot] = mn;
        mxp[slot] = mx;
    }
}

// ---------------- K3: scrambled gather + fused renorm + Wp projection ----------------
// grid 2048; block 256; 32 positions/block, 4 gathers+outputs per thread
__global__ __launch_bounds__(256) void k_proj(const float* __restrict__ oraw,
    const float* __restrict__ mnp, const float* __restrict__ mxp,
    const float* __restrict__ Wp, const float* __restrict__ bp,
    float* __restrict__ out)
{
    __shared__ float Wp_s[1024], bp_s[32];
    __shared__ float sh_v[32][33];       // padded: kills 8-way bank conflict
    __shared__ float sh_o[32][33];
    int t = threadIdx.x;
    if (t < 32) bp_s[t] = bp[t];
    for (int L = t; L < 1024; L += 256) Wp_s[L] = Wp[L];
    int blk = blockIdx.x;
    int b = blk >> 10, p0 = (blk & 1023) * 32;
    int c = t & 31, ip0 = t >> 5;
    float vv[4];
    #pragma unroll
    for (int m = 0; m < 4; ++m){
        int p = p0 + m*8 + ip0;
        int h = p >> 10, w = (p >> 5) & 31, dsp = p & 31;
        int f = (h >> 3)*262144 + (w >> 3)*65536 + (dsp >> 3)*16384
              + (h & 7)*2048 + (w & 7)*256 + (dsp & 7)*32;
        int flat = f + c;
        int cidx = b*2048 + (flat >> 9);         // bg*32 + channel
        int s0 = ((cidx >> 5) << 7) + (cidx & 31);
        float o  = oraw[(size_t)b*1048576 + flat];
        float mn = fminf(fminf(mnp[s0], mnp[s0 + 32]), fminf(mnp[s0 + 64], mnp[s0 + 96]));
        float mx = fmaxf(fmaxf(mxp[s0], mxp[s0 + 32]), fmaxf(mxp[s0 + 64], mxp[s0 + 96]));
        vv[m] = (o - mn) / (mx - mn + 1e-4f);
    }
    __syncthreads();
    #pragma unroll
    for (int m = 0; m < 4; ++m) sh_v[m*8 + ip0][c] = vv[m];
    __syncthreads();
    #pragma unroll
    for (int m = 0; m < 4; ++m){
        int pos = m*8 + ip0;
        float acc = bp_s[c];
        #pragma unroll
        for (int cc = 0; cc < 32; ++cc)
            acc += sh_v[pos][cc] * Wp_s[cc*32 + c];
        sh_o[pos][c] = acc;
    }
    __syncthreads();
    #pragma unroll
    for (int m = 0; m < 4; ++m){
        int e = m*8 + (t >> 5), pi = t & 31;
        out[((size_t)(b*32 + e) << 15) + p0 + pi] = sh_o[pi][e];
    }
}

extern "C" void kernel_launch(void* const* d_in, const int* in_sizes, int n_in,
                              void* d_out, int out_size, void* d_ws, size_t ws_size,
                              hipStream_t stream)
{
    const float* q  = (const float*)d_in[0];
    const float* k  = (const float*)d_in[1];
    const float* Wq = (const float*)d_in[2];
    const float* bq = (const float*)d_in[3];
    const float* Wk = (const float*)d_in[4];
    const float* bk = (const float*)d_in[5];
    const float* Wp = (const float*)d_in[6];
    const float* bp = (const float*)d_in[7];

    float* base      = (float*)d_ws;
    uint32_t* kf_img = (uint32_t*)base;                // 16384 u32
    uint32_t* qb_img = (uint32_t*)(base + 16384);      // 1,048,576 u32
    float* oraw      = base + 1064960;                 // 2,097,152 f
    float* mnp       = base + 3162112;                 // 16384 f
    float* mxp       = base + 3178496;                 // 16384 f (~12.8 MB total)
    float* outp      = (float*)d_out;

    hipLaunchKernelGGL(k_pre,       dim3(512),  dim3(1024), 0, stream, q, k, Wq, bq, Wk, bk, qb_img, kf_img);
    hipLaunchKernelGGL(k_attn_mfma, dim3(512),  dim3(512),  0, stream, kf_img, qb_img, oraw, mnp, mxp);
    hipLaunchKernelGGL(k_proj,      dim3(2048), dim3(256),  0, stream, oraw, mnp, mxp, Wp, bp, outp);
}